// Round 14
// baseline (110.874 us; speedup 1.0000x reference)
//
#include <hip/hip_runtime.h>
#include <hip/hip_bf16.h>

#define B_    8
#define N_    9225
#define M_    4096
#define K_    32
#define HID_  64
#define DOUT_ 16
#define SENT  (B_ * N_)          // sentinel record index (all zeros)

typedef __attribute__((ext_vector_type(8))) short short8;
typedef __attribute__((ext_vector_type(4))) float floatx4;
typedef __attribute__((ext_vector_type(2))) float f32x2;

static __device__ __forceinline__ short f2bf(float f) {
    __hip_bfloat16 h = __float2bfloat16(f);
    return __builtin_bit_cast(short, h);
}
static __device__ __forceinline__ unsigned pack2bf(float a, float b) {
    const unsigned lo = (unsigned)(unsigned short)__builtin_bit_cast(short, __float2bfloat16(a));
    const unsigned hi = (unsigned)(unsigned short)__builtin_bit_cast(short, __float2bfloat16(b));
    return (hi << 16) | lo;
}
static __device__ __forceinline__ f32x2 splat2(float v) { return (f32x2){v, v}; }
static __device__ __forceinline__ int bpermi(int src_bytes, int v) {
    return __builtin_amdgcn_ds_bpermute(src_bytes, v);
}

// Sum over each 16-lane DPP row via row_shr tree; lane (row*16+15) holds the sum.
static __device__ __forceinline__ float row16_sum(float v) {
    int t;
    t = __builtin_amdgcn_update_dpp(0, __builtin_bit_cast(int, v), 0x111, 0xF, 0xF, true);
    v += __builtin_bit_cast(float, t);
    t = __builtin_amdgcn_update_dpp(0, __builtin_bit_cast(int, v), 0x112, 0xF, 0xF, true);
    v += __builtin_bit_cast(float, t);
    t = __builtin_amdgcn_update_dpp(0, __builtin_bit_cast(int, v), 0x114, 0xF, 0xF, true);
    v += __builtin_bit_cast(float, t);
    t = __builtin_amdgcn_update_dpp(0, __builtin_bit_cast(int, v), 0x118, 0xF, 0xF, true);
    v += __builtin_bit_cast(float, t);
    return v;
}

// gelu(x) ~ 0.5*x*(1 + tanh(z)), z = x*(0.79788456 + 0.035677408*x^2),
// tanh via Pade(5,4), clamped to [-1,1]. No v_exp. (Validated R4-R13.)
static __device__ __forceinline__ f32x2 gelu2(f32x2 x) {
    const f32x2 xsq = x * x;
    const f32x2 t   = __builtin_elementwise_fma(xsq, splat2(0.035677408f), splat2(0.79788456f));
    const f32x2 z   = x * t;
    const f32x2 u   = z * z;
    const f32x2 a   = u + splat2(105.0f);
    const f32x2 nin = __builtin_elementwise_fma(u, a, splat2(945.0f));
    const f32x2 num = z * nin;
    const f32x2 bq  = __builtin_elementwise_fma(u, splat2(15.0f), splat2(420.0f));
    const f32x2 den = __builtin_elementwise_fma(u, bq, splat2(945.0f));
    const f32x2 r   = { __builtin_amdgcn_rcpf(den[0]), __builtin_amdgcn_rcpf(den[1]) };
    f32x2 th = num * r;
    th = __builtin_elementwise_min(__builtin_elementwise_max(th, splat2(-1.0f)), splat2(1.0f));
    const f32x2 hx = x * splat2(0.5f);
    return __builtin_elementwise_fma(hx, th, hx);
}

// PREP: build 64B record per (b,n) in d_ws. Chunk c (16B) =
//   { bf16 f_y[4c..4c+3] (8B), bf16 y.x,y.y (4B), f32 w (4B) }  (y/w replicated).
// Record SENT (index B_*N_) is all zeros: invalid neighbors point here (w=0
// kills the term). Thread t = (record n = t>>2, chunk c = t&3): fully
// coalesced dwordx4 read of f_y, dwordx4 write of pack.
__global__ __launch_bounds__(256) void prep_kernel(
    const float* __restrict__ y,
    const float* __restrict__ f_y,
    const float* __restrict__ w,
    unsigned*    __restrict__ pack)
{
    const int t = blockIdx.x * 256 + threadIdx.x;
    const int n = t >> 2, c = t & 3;
    if (n > SENT) return;
    uint4 o = {0u, 0u, 0u, 0u};
    if (n < SENT) {
        const floatx4 f = *(const floatx4*)(f_y + (size_t)n * 16 + c * 4);
        o.x = pack2bf(f[0], f[1]);
        o.y = pack2bf(f[2], f[3]);
        const float2 yv = *(const float2*)(y + (size_t)n * 2);
        o.z = pack2bf(yv.x, yv.y);
        o.w = __builtin_bit_cast(unsigned, w[n]);
    }
    *(uint4*)(pack + (size_t)n * 16 + c * 4) = o;
}

// MAIN (R13 double-MFMA structure + packed gather stream):
// R2-R13 all pinned at ~41us = ~98k cyc: per-wave line demand ~170 (f_y 64 +
// y ~50 + w ~50 + nbr 4) at the ~0.11-0.17 lines/cyc/CU vector-memory line
// throughput ceiling. This round: ONE dwordx4 per lane per phase fetches
// f_y-slice+y+w together from the packed record -> 16 lines/phase, ~70
// lines/wave total (2.4x cut). y/w dedup gather and 3 of 4 bperms deleted.
__global__ __launch_bounds__(256) void it_kernel(
    const float*    __restrict__ x,
    const float*    __restrict__ W1,   // [4][64] row-major
    const float*    __restrict__ b1,   // [64]
    const float*    __restrict__ W2,   // [64][16] row-major
    const float*    __restrict__ b2,   // [16]
    const int*      __restrict__ nbr,  // [B][M][K] int32
    const unsigned* __restrict__ pack, // [(B*N)+1][16] uints (64B records)
    float*          __restrict__ out)  // [B][M][16]
{
    const int tid  = threadIdx.x;
    const int lane = tid & 63;
    const int q    = lane >> 4;    // quad 0..3
    const int nlo  = lane & 15;    // neighbor-within-half; also c/m for MFMAs
    // ---- XCD-pinned mapping: batch = blk & 7 (round-robin XCD heuristic) ----
    const int blk   = blockIdx.x;
    const int batch = blk & 7;
    const int pidx  = (blk >> 3) * 4 + (tid >> 6);   // pair index within batch
    const int row0  = __builtin_amdgcn_readfirstlane(batch * M_ + pidx * 2);
    const int bbase = batch * N_;

    // ---- dedup nbr read: lane g covers (row g>>5, neighbor g&31) ----
    const int r_g = lane >> 5, kk = lane & 31;
    const int raw = nbr[(size_t)(row0 + r_g) * K_ + kk];
    const int bn_g = (raw >= 0) ? (bbase + raw) : SENT;

    // ---- MFMA-1 A-frags: a1f[t], A[m=nlo (hid=t*16+nlo)][k=q*8+jj] ----
    // k<4: W1[k][t*16+nlo]; k==4: b1[t*16+nlo]; else 0. (q>=1 lanes all 0.)
    short8 a1f[4];
    #pragma unroll
    for (int t = 0; t < 4; ++t) {
        #pragma unroll
        for (int jj = 0; jj < 8; ++jj) {
            const int k = q * 8 + jj;
            float v = 0.0f;
            if (k < 4)       v = W1[k * 64 + t * 16 + nlo];
            else if (k == 4) v = b1[t * 16 + nlo];
            a1f[t][jj] = f2bf(v);
        }
    }

    // ---- W2 A-frag under the j-bijection: w2f[ch][jj] = W2[j][nlo],
    //      j = (ch*2 + (jj>>2))*16 + q*4 + (jj&3) ----
    short8 w2f[2];
    #pragma unroll
    for (int ch = 0; ch < 2; ++ch)
        #pragma unroll
        for (int jj = 0; jj < 8; ++jj) {
            const int j = (ch * 2 + (jj >> 2)) * 16 + q * 4 + (jj & 3);
            w2f[ch][jj] = f2bf(W2[j * DOUT_ + nlo]);
        }

    const floatx4 b2v = *(const floatx4*)(b2 + q * 4);
    const short one_bf = f2bf(1.0f);

    // x as bf16 per row (for the MFMA-1 B-frag)
    const float2 xv0 = *(const float2*)(x + (size_t)row0 * 2);
    const float2 xv1 = *(const float2*)(x + (size_t)row0 * 2 + 2);
    const short xb[2][2] = { { f2bf(xv0.x), f2bf(xv0.y) },
                             { f2bf(xv1.x), f2bf(xv1.y) } };

    float partial[4] = {0.f, 0.f, 0.f, 0.f};
    #pragma unroll
    for (int ph = 0; ph < 4; ++ph) {
        const int it = ph >> 1, h = ph & 1;
        const int src = ((it << 5) + (h << 4) + nlo) << 2;

        // ---- ONE gather: this lane's chunk of its phase-neighbor's record ----
        const int bn = bpermi(src, bn_g);
        const uint4 rec = *(const uint4*)(pack + (size_t)bn * 16 + q * 4);

        // unpack: fv (4 channels), s, y pair (bf16 shorts, MFMA-ready)
        const float fv0 = __builtin_bit_cast(float, rec.x << 16);
        const float fv1 = __builtin_bit_cast(float, rec.x & 0xffff0000u);
        const float fv2 = __builtin_bit_cast(float, rec.y << 16);
        const float fv3 = __builtin_bit_cast(float, rec.y & 0xffff0000u);
        const float s   = __builtin_bit_cast(float, rec.w);

        // ---- MFMA-1 B-frag: agg column of this lane's neighbor (q=0 only) ----
        short8 bfrag = {0, 0, 0, 0, 0, 0, 0, 0};
        if (q == 0) {
            bfrag[0] = (short)(rec.z & 0xffffu);
            bfrag[1] = (short)(rec.z >> 16);
            bfrag[2] = xb[it][0];
            bfrag[3] = xb[it][1];
            bfrag[4] = one_bf;
        }

        // ---- 4x MFMA-1: H tiles, lane(q,nlo) gets H[t*16+q*4+r][nlo] ----
        floatx4 accT[4];
        #pragma unroll
        for (int t = 0; t < 4; ++t) {
            floatx4 z4 = {0.f, 0.f, 0.f, 0.f};
            accT[t] = __builtin_amdgcn_mfma_f32_16x16x32_bf16(a1f[t], bfrag, z4, 0, 0, 0);
        }

        // ---- gelu + repack into W2 B-frag (j-bijection jj=(t&1)*4+r) ----
        short8 hf[2];
        #pragma unroll
        for (int ch = 0; ch < 2; ++ch)
            #pragma unroll
            for (int half = 0; half < 2; ++half) {
                const floatx4 a = accT[ch * 2 + half];
                const f32x2 g0 = gelu2((f32x2){a[0], a[1]});
                const f32x2 g1 = gelu2((f32x2){a[2], a[3]});
                hf[ch][half * 4 + 0] = f2bf(g0[0]);
                hf[ch][half * 4 + 1] = f2bf(g0[1]);
                hf[ch][half * 4 + 2] = f2bf(g1[0]);
                hf[ch][half * 4 + 3] = f2bf(g1[1]);
            }

        // ---- MFMA-2: C' = W2^T x g^T, acc preloaded with b2 ----
        floatx4 acc = b2v;
        acc = __builtin_amdgcn_mfma_f32_16x16x32_bf16(w2f[0], hf[0], acc, 0, 0, 0);
        acc = __builtin_amdgcn_mfma_f32_16x16x32_bf16(w2f[1], hf[1], acc, 0, 0, 0);
        partial[0] = fmaf(acc[0], fv0 * s, partial[0]);
        partial[1] = fmaf(acc[1], fv1 * s, partial[1]);
        partial[2] = fmaf(acc[2], fv2 * s, partial[2]);
        partial[3] = fmaf(acc[3], fv3 * s, partial[3]);

        if (h == 1) {   // finished a row: reduce over 16 neighbors, store
            #pragma unroll
            for (int r4 = 0; r4 < 4; ++r4)
                partial[r4] = row16_sum(partial[r4]);
            if (nlo == 15) {
                floatx4 o = {partial[0], partial[1], partial[2], partial[3]};
                *(floatx4*)(out + (size_t)(row0 + it) * DOUT_ + q * 4) = o;
            }
            #pragma unroll
            for (int r4 = 0; r4 < 4; ++r4) partial[r4] = 0.f;
        }
    }
}

extern "C" void kernel_launch(void* const* d_in, const int* in_sizes, int n_in,
                              void* d_out, int out_size, void* d_ws, size_t ws_size,
                              hipStream_t stream) {
    const float* y   = (const float*)d_in[0];
    const float* x   = (const float*)d_in[1];
    const float* f_y = (const float*)d_in[2];
    const float* w   = (const float*)d_in[3];
    const float* W1  = (const float*)d_in[4];
    const float* b1  = (const float*)d_in[5];
    const float* W2  = (const float*)d_in[6];
    const float* b2  = (const float*)d_in[7];
    const int*   nbr = (const int*)d_in[8];
    float* out = (float*)d_out;
    unsigned* pack = (unsigned*)d_ws;   // (B*N+1) x 64B records

    // prep: (B*N+1) records x 4 chunks, one thread per chunk
    const int nthread = (SENT + 1) * 4;
    dim3 pgrid((nthread + 255) / 256), pblock(256);
    hipLaunchKernelGGL(prep_kernel, pgrid, pblock, 0, stream, y, f_y, w, pack);

    // main: 4096 blocks, 512 per batch, batch = blockIdx % 8 -> XCD pinned
    dim3 grid(B_ * M_ / 8), block(256);
    hipLaunchKernelGGL(it_kernel, grid, block, 0, stream,
                       x, W1, b1, W2, b2, nbr, pack, out);
}